// Round 4
// baseline (242.126 us; speedup 1.0000x reference)
//
#include <hip/hip_runtime.h>
#include <cstdint>
#include <cstddef>

typedef unsigned short u16;
typedef short short8 __attribute__((ext_vector_type(8)));
typedef float floatx4 __attribute__((ext_vector_type(4)));

#define DEVINL __device__ __forceinline__

static constexpr int BSZ = 8, SEQL = 4096, H = 512, P = 256;
static constexpr int M = BSZ * SEQL;       // 32768 rows
static constexpr int KD = 512;             // K for both GEMMs
static constexpr int ND = 512;             // N for both GEMMs
static constexpr int CHUNK = 32;           // scan chunk (one 64B line per row per thread)
static constexpr int NCH = SEQL / CHUNK;   // 128 chunks

DEVINL u16 f2bf(float f) {
  union { float f; unsigned u; } v; v.f = f;
  unsigned r = (v.u + 0x7fffu + ((v.u >> 16) & 1u)) >> 16;
  return (u16)r;
}
DEVINL float bf2f(u16 h) {
  union { unsigned u; float f; } v; v.u = ((unsigned)h) << 16; return v.f;
}

// async global->LDS, 16B per lane. LDS dest must be wave-uniform base + lane*16.
DEVINL void gload_lds16(const u16* g, u16* l) {
  __builtin_amdgcn_global_load_lds(
      (const __attribute__((address_space(1))) unsigned*)g,
      (__attribute__((address_space(3))) unsigned*)l, 16, 0, 0);
}

// ---------- setup: lam[p] = exp(Lambda*step), f[p] = (lam-1)/Lambda ----------
__global__ void setup_kernel(const float* __restrict__ Lre, const float* __restrict__ Lim,
                             const float* __restrict__ logstep,
                             float2* __restrict__ lam, float2* __restrict__ ffac) {
  int p = threadIdx.x;
  if (p >= P) return;
  float lr = Lre[p], li = Lim[p];
  float st = expf(logstep[p]);
  float mag = expf(lr * st);
  float ang = li * st;
  float cr = mag * cosf(ang);
  float ci = mag * sinf(ang);
  lam[p] = make_float2(cr, ci);
  float a = cr - 1.0f, b = ci;
  float den = lr * lr + li * li;
  float fr = (a * lr + b * li) / den;
  float fi = (b * lr - a * li) / den;
  ffac[p] = make_float2(fr, fi);
}

// ---------- Bt1[n=2p+ri][h] = component of f[p]*B_tilde[p][h], bf16 ----------
__global__ void bt1_kernel(const float2* __restrict__ Bin,
                           const float2* __restrict__ ffac,
                           u16* __restrict__ bt1) {
  int idx = blockIdx.x * 256 + threadIdx.x;   // over P*H
  int p = idx / H, h = idx % H;
  float2 bv = Bin[(size_t)p * H + h];
  float2 f = ffac[p];
  float br = f.x * bv.x - f.y * bv.y;
  float bi = f.x * bv.y + f.y * bv.x;
  bt1[(size_t)(2 * p) * H + h]     = f2bf(br);
  bt1[(size_t)(2 * p + 1) * H + h] = f2bf(bi);
}

// ---------- Bt2[h][2p+ri] = +-2 * C[h][p][ri] ----------
__global__ void bt2_kernel(const float* __restrict__ Cin, u16* __restrict__ bt2) {
  int idx = blockIdx.x * 256 + threadIdx.x;   // over H*P*2
  float c = Cin[idx];
  float v = (idx & 1) ? -2.0f * c : 2.0f * c;
  bt2[idx] = f2bf(v);
}

// ---------- u (f32) -> u_bf (bf16), 4 per thread ----------
__global__ void ucvt_kernel(const float4* __restrict__ uin, ushort4* __restrict__ ubf) {
  int idx = blockIdx.x * 256 + threadIdx.x;   // over M*H/4
  float4 f = uin[idx];
  ushort4 o;
  o.x = f2bf(f.x); o.y = f2bf(f.y); o.z = f2bf(f.z); o.w = f2bf(f.w);
  ubf[idx] = o;
}

// ---------- MFMA GEMM, BK=64: C[M][N] = A[M][K]*Bt[N][K]^T ----------
// LDS chunk swizzle: physical chunk = logical ^ (row&7), applied on the global
// source column (global_load_lds dest fixed) and on the ds_read index.
// MODE 0: store bf16 TRANSPOSED Bu_t[b][n][l] (n-major), 8B ushort4 per (tm,tn).
// MODE 1: ys = acc + D[n]*u32[m][n], gelu, f32 out (normal [m][n] layout).
template <int MODE>
__global__ __launch_bounds__(256, 4) void gemm_bt(const u16* __restrict__ A,
                                                  const u16* __restrict__ Bt,
                                                  u16* __restrict__ outBf,
                                                  float* __restrict__ outF,
                                                  const float* __restrict__ Dv,
                                                  const float* __restrict__ u32) {
  __shared__ u16 As[128 * 64];   // 16 KB
  __shared__ u16 Bs[128 * 64];   // 16 KB
  const int tid = threadIdx.x;
  const int bm = blockIdx.x, bn = blockIdx.y;
  const int wave = tid >> 6, lane = tid & 63;
  const int quad = lane >> 4, l16 = lane & 15;
  const int wm = (wave & 1) << 6, wn = (wave >> 1) << 6;
  const int r7 = l16 & 7;

  floatx4 acc[4][4] = {};

  const u16* Ab = A + (size_t)bm * 128 * KD;
  const u16* Bb = Bt + (size_t)bn * 128 * KD;
  const int srow = tid >> 3;                                  // 0..31
  const int scol = (((tid & 7) ^ ((tid >> 3) & 7)) << 3);     // swizzled src col

  for (int k0 = 0; k0 < KD; k0 += 64) {
    __syncthreads();
#pragma unroll
    for (int j = 0; j < 4; j++)
      gload_lds16(Ab + (size_t)(j * 32 + srow) * KD + k0 + scol, &As[j * 2048 + tid * 8]);
#pragma unroll
    for (int j = 0; j < 4; j++)
      gload_lds16(Bb + (size_t)(j * 32 + srow) * KD + k0 + scol, &Bs[j * 2048 + tid * 8]);
    __syncthreads();

#pragma unroll
    for (int h = 0; h < 2; h++) {
      const int pc = (((h << 2) | quad) ^ r7) << 3;   // physical col offset
      short8 af[4], bfr[4];
#pragma unroll
      for (int t = 0; t < 4; t++)
        af[t] = *(const short8*)&As[(wm + t * 16 + l16) * 64 + pc];
#pragma unroll
      for (int t = 0; t < 4; t++)
        bfr[t] = *(const short8*)&Bs[(wn + t * 16 + l16) * 64 + pc];
#pragma unroll
      for (int tm = 0; tm < 4; tm++)
#pragma unroll
        for (int tn = 0; tn < 4; tn++)
          acc[tm][tn] = __builtin_amdgcn_mfma_f32_16x16x32_bf16(af[tm], bfr[tn], acc[tm][tn], 0, 0, 0);
    }
  }

  // epilogue: C/D layout col = lane&15, row = quad*4 + reg  [m89-verified]
  const int row_base = bm * 128 + wm + quad * 4;
  const int col_base = bn * 128 + wn + l16;
  float dv[4];
  if (MODE == 1) {
#pragma unroll
    for (int tn = 0; tn < 4; tn++) dv[tn] = Dv[col_base + tn * 16];
  }
#pragma unroll
  for (int tm = 0; tm < 4; tm++) {
#pragma unroll
    for (int tn = 0; tn < 4; tn++) {
      int n = col_base + tn * 16;
      if (MODE == 0) {
        // transposed store: rows r are consecutive l -> one 8B ushort4
        int mrow = row_base + tm * 16;            // multiple of 4; same batch for r=0..3
        ushort4 pk;
        pk.x = f2bf(acc[tm][tn][0]); pk.y = f2bf(acc[tm][tn][1]);
        pk.z = f2bf(acc[tm][tn][2]); pk.w = f2bf(acc[tm][tn][3]);
        size_t addr = ((size_t)(mrow >> 12) * ND + n) * SEQL + (mrow & (SEQL - 1));
        *(ushort4*)&outBf[addr] = pk;
      } else {
#pragma unroll
        for (int r = 0; r < 4; r++) {
          int m = row_base + tm * 16 + r;
          float uv = u32[(size_t)m * ND + n];
          float ys = acc[tm][tn][r] + dv[tn] * uv;
          float y3 = ys * ys * ys;
          float t = tanhf(0.7978845608028654f * (ys + 0.044715f * y3));
          outF[(size_t)m * ND + n] = 0.5f * ys * (1.0f + t);
        }
      }
    }
  }
}

// ---------- scan pass 1: per-chunk carries (reads transposed Bu_t) ----------
// thread p reads rows 2p (re) and 2p+1 (im), cols [c*32, c*32+32) = one 64B line each
__global__ __launch_bounds__(256) void scan_carry(const u16* __restrict__ But,
                                                  const float2* __restrict__ lam,
                                                  float2* __restrict__ carry) {
  int p = threadIdx.x;
  int c = blockIdx.x;
  int b = blockIdx.y;
  float2 lm = lam[p];
  const u16* rr = But + ((size_t)b * ND + 2 * p) * SEQL + c * CHUNK;
  const u16* ri = rr + SEQL;
  short8 rv[4], iv[4];
#pragma unroll
  for (int j = 0; j < 4; j++) rv[j] = *(const short8*)(rr + 8 * j);
#pragma unroll
  for (int j = 0; j < 4; j++) iv[j] = *(const short8*)(ri + 8 * j);
  float xr = 0.f, xi = 0.f;
#pragma unroll
  for (int l = 0; l < CHUNK; l++) {
    float br = bf2f((u16)rv[l >> 3][l & 7]);
    float bi = bf2f((u16)iv[l >> 3][l & 7]);
    float nr = lm.x * xr - lm.y * xi + br;
    float ni = lm.x * xi + lm.y * xr + bi;
    xr = nr; xi = ni;
  }
  carry[((size_t)b * NCH + c) * P + p] = make_float2(xr, xi);
}

// ---------- scan pass 2: sequential prefix over chunks ----------
__global__ __launch_bounds__(256) void scan_prefix(const float2* __restrict__ carry,
                                                   const float2* __restrict__ lam,
                                                   float2* __restrict__ prefix) {
  int p = threadIdx.x;
  int b = blockIdx.x;
  float2 lm = lam[p];
  float ar = lm.x, ai = lm.y;
  // lam^CHUNK, CHUNK = 32 = 2^5
#pragma unroll
  for (int i = 0; i < 5; i++) { float nr = ar * ar - ai * ai, ni = 2.f * ar * ai; ar = nr; ai = ni; }
  float pr = 0.f, pi = 0.f;
  for (int c = 0; c < NCH; c++) {
    prefix[((size_t)b * NCH + c) * P + p] = make_float2(pr, pi);
    float2 ca = carry[((size_t)b * NCH + c) * P + p];
    float nr = ar * pr - ai * pi + ca.x;
    float ni = ar * pi + ai * pr + ca.y;
    pr = nr; pi = ni;
  }
}

// ---------- scan pass 3: apply prefix; read Bu_t (transposed), write xs [m][k] ----------
__global__ __launch_bounds__(256) void scan_apply(const u16* __restrict__ But,
                                                  const float2* __restrict__ lam,
                                                  const float2* __restrict__ prefix,
                                                  u16* __restrict__ xs) {
  int p = threadIdx.x;
  int c = blockIdx.x;
  int b = blockIdx.y;
  float2 lm = lam[p];
  const u16* rr = But + ((size_t)b * ND + 2 * p) * SEQL + c * CHUNK;
  const u16* ri = rr + SEQL;
  short8 rv[4], iv[4];
#pragma unroll
  for (int j = 0; j < 4; j++) rv[j] = *(const short8*)(rr + 8 * j);
#pragma unroll
  for (int j = 0; j < 4; j++) iv[j] = *(const short8*)(ri + 8 * j);
  float2 pf = prefix[((size_t)b * NCH + c) * P + p];
  float xr = pf.x, xi = pf.y;
  unsigned* orow = (unsigned*)(xs + ((size_t)b * SEQL + (size_t)c * CHUNK) * ND) + p;
#pragma unroll
  for (int l = 0; l < CHUNK; l++) {
    float br = bf2f((u16)rv[l >> 3][l & 7]);
    float bi = bf2f((u16)iv[l >> 3][l & 7]);
    float nr = lm.x * xr - lm.y * xi + br;
    float ni = lm.x * xi + lm.y * xr + bi;
    xr = nr; xi = ni;
    orow[(size_t)l * (ND / 2)] = (unsigned)f2bf(nr) | ((unsigned)f2bf(ni) << 16);
  }
}

extern "C" void kernel_launch(void* const* d_in, const int* in_sizes, int n_in,
                              void* d_out, int out_size, void* d_ws, size_t ws_size,
                              hipStream_t stream) {
  const float* u      = (const float*)d_in[0];   // (8,4096,512)
  const float* Lre    = (const float*)d_in[1];   // (256,)
  const float* Lim    = (const float*)d_in[2];   // (256,)
  const float* Bin    = (const float*)d_in[3];   // (256,512,2)
  const float* Cin    = (const float*)d_in[4];   // (512,256,2)
  const float* Dv     = (const float*)d_in[5];   // (512,)
  const float* lstep  = (const float*)d_in[6];   // (256,1)
  float* out          = (float*)d_out;           // (8,4096,512) f32

  char* ws = (char*)d_ws;
  float2* lam    = (float2*)(ws + 0);                 //   2 KB
  float2* ffac   = (float2*)(ws + 2048);              //   2 KB
  u16*    bt1    = (u16*)   (ws + 4096);              // 512 KB
  u16*    bt2    = (u16*)   (ws + 528384);            // 512 KB
  u16*    ubf    = (u16*)   (ws + 1052672);           //  32 MB (u bf16; later xs)
  u16*    But    = (u16*)   (ws + 34607104);          //  32 MB transposed Bu
  float2* carry  = (float2*)(ws + 68161536);          //   2 MB
  float2* prefix = (float2*)(ws + 70258688);          //   2 MB

  setup_kernel<<<1, 256, 0, stream>>>(Lre, Lim, lstep, lam, ffac);
  bt1_kernel<<<(P * H) / 256, 256, 0, stream>>>((const float2*)Bin, ffac, bt1);
  bt2_kernel<<<(H * P * 2) / 256, 256, 0, stream>>>(Cin, bt2);
  ucvt_kernel<<<(M * H / 4) / 256, 256, 0, stream>>>((const float4*)u, (ushort4*)ubf);

  gemm_bt<0><<<dim3(M / 128, ND / 128), 256, 0, stream>>>(ubf, bt1, But, nullptr, nullptr, nullptr);

  scan_carry <<<dim3(NCH, BSZ), 256, 0, stream>>>(But, lam, carry);
  scan_prefix<<<BSZ, 256, 0, stream>>>(carry, lam, prefix);
  scan_apply <<<dim3(NCH, BSZ), 256, 0, stream>>>(But, lam, prefix, ubf);  // xs -> ubf buffer

  gemm_bt<1><<<dim3(M / 128, ND / 128), 256, 0, stream>>>(ubf, bt2, nullptr, out, Dv, u);
}

// Round 5
// 217.939 us; speedup vs baseline: 1.1110x; 1.1110x over previous
//
#include <hip/hip_runtime.h>
#include <cstdint>
#include <cstddef>

typedef unsigned short u16;
typedef short short8 __attribute__((ext_vector_type(8)));
typedef float floatx4 __attribute__((ext_vector_type(4)));

#define DEVINL __device__ __forceinline__

static constexpr int BSZ = 8, SEQL = 4096, H = 512, P = 256;
static constexpr int M = BSZ * SEQL;       // 32768 rows
static constexpr int KD = 512;             // K for both GEMMs
static constexpr int ND = 512;             // N for both GEMMs
static constexpr int CHUNK = 32;           // scan chunk
static constexpr int NCH = SEQL / CHUNK;   // 128 chunks

DEVINL u16 f2bf(float f) {
  union { float f; unsigned u; } v; v.f = f;
  unsigned r = (v.u + 0x7fffu + ((v.u >> 16) & 1u)) >> 16;
  return (u16)r;
}
DEVINL float bf2f(u16 h) {
  union { unsigned u; float f; } v; v.u = ((unsigned)h) << 16; return v.f;
}

// async global->LDS, 16B per lane. LDS dest must be wave-uniform base + lane*16.
DEVINL void gload_lds16(const u16* g, u16* l) {
  __builtin_amdgcn_global_load_lds(
      (const __attribute__((address_space(1))) unsigned*)g,
      (__attribute__((address_space(3))) unsigned*)l, 16, 0, 0);
}

// ---------- setup: lam[p] = exp(Lambda*step), f[p] = (lam-1)/Lambda ----------
__global__ void setup_kernel(const float* __restrict__ Lre, const float* __restrict__ Lim,
                             const float* __restrict__ logstep,
                             float2* __restrict__ lam, float2* __restrict__ ffac) {
  int p = threadIdx.x;
  if (p >= P) return;
  float lr = Lre[p], li = Lim[p];
  float st = expf(logstep[p]);
  float mag = expf(lr * st);
  float ang = li * st;
  float cr = mag * cosf(ang);
  float ci = mag * sinf(ang);
  lam[p] = make_float2(cr, ci);
  float a = cr - 1.0f, b = ci;
  float den = lr * lr + li * li;
  float fr = (a * lr + b * li) / den;
  float fi = (b * lr - a * li) / den;
  ffac[p] = make_float2(fr, fi);
}

// ---------- Bt1[n=2p+ri][h] = component of f[p]*B_tilde[p][h], bf16 ----------
__global__ void bt1_kernel(const float2* __restrict__ Bin,
                           const float2* __restrict__ ffac,
                           u16* __restrict__ bt1) {
  int idx = blockIdx.x * 256 + threadIdx.x;   // over P*H
  int p = idx / H, h = idx % H;
  float2 bv = Bin[(size_t)p * H + h];
  float2 f = ffac[p];
  float br = f.x * bv.x - f.y * bv.y;
  float bi = f.x * bv.y + f.y * bv.x;
  bt1[(size_t)(2 * p) * H + h]     = f2bf(br);
  bt1[(size_t)(2 * p + 1) * H + h] = f2bf(bi);
}

// ---------- Bt2[h][2p+ri] = +-2 * C[h][p][ri] ----------
__global__ void bt2_kernel(const float* __restrict__ Cin, u16* __restrict__ bt2) {
  int idx = blockIdx.x * 256 + threadIdx.x;   // over H*P*2
  float c = Cin[idx];
  float v = (idx & 1) ? -2.0f * c : 2.0f * c;
  bt2[idx] = f2bf(v);
}

// ---------- u (f32) -> u_bf (bf16), 8 per thread, 16B stores ----------
__global__ void ucvt_kernel(const float4* __restrict__ uin, short8* __restrict__ ubf) {
  int idx = blockIdx.x * 256 + threadIdx.x;   // over M*H/8
  float4 f0 = uin[2 * idx];
  float4 f1 = uin[2 * idx + 1];
  short8 o;
  o[0] = f2bf(f0.x); o[1] = f2bf(f0.y); o[2] = f2bf(f0.z); o[3] = f2bf(f0.w);
  o[4] = f2bf(f1.x); o[5] = f2bf(f1.y); o[6] = f2bf(f1.z); o[7] = f2bf(f1.w);
  ubf[idx] = o;
}

// ---------- MFMA GEMM, BK=64: C[M][N] = A[M][K]*Bt[N][K]^T ----------
// LDS chunk swizzle: physical chunk = logical ^ (row&7), applied on the global
// source column (global_load_lds dest fixed) and on the ds_read index.
// MODE 0: store bf16 [m][n] (plain 2B stores).
// MODE 1: ys = acc + D[n]*bf2f(ubf[m][n]), gelu, f32 out.
template <int MODE>
__global__ __launch_bounds__(256, 4) void gemm_bt(const u16* __restrict__ A,
                                                  const u16* __restrict__ Bt,
                                                  u16* __restrict__ outBf,
                                                  float* __restrict__ outF,
                                                  const float* __restrict__ Dv,
                                                  const u16* __restrict__ ubf) {
  __shared__ u16 As[128 * 64];   // 16 KB
  __shared__ u16 Bs[128 * 64];   // 16 KB
  const int tid = threadIdx.x;
  const int bm = blockIdx.x, bn = blockIdx.y;
  const int wave = tid >> 6, lane = tid & 63;
  const int quad = lane >> 4, l16 = lane & 15;
  const int wm = (wave & 1) << 6, wn = (wave >> 1) << 6;
  const int r7 = l16 & 7;

  floatx4 acc[4][4] = {};

  const u16* Ab = A + (size_t)bm * 128 * KD;
  const u16* Bb = Bt + (size_t)bn * 128 * KD;
  const int srow = tid >> 3;                                  // 0..31
  const int scol = (((tid & 7) ^ ((tid >> 3) & 7)) << 3);     // swizzled src col

  for (int k0 = 0; k0 < KD; k0 += 64) {
    __syncthreads();
#pragma unroll
    for (int j = 0; j < 4; j++)
      gload_lds16(Ab + (size_t)(j * 32 + srow) * KD + k0 + scol, &As[j * 2048 + tid * 8]);
#pragma unroll
    for (int j = 0; j < 4; j++)
      gload_lds16(Bb + (size_t)(j * 32 + srow) * KD + k0 + scol, &Bs[j * 2048 + tid * 8]);
    __syncthreads();

#pragma unroll
    for (int h = 0; h < 2; h++) {
      const int pc = (((h << 2) | quad) ^ r7) << 3;   // physical col offset
      short8 af[4], bfr[4];
#pragma unroll
      for (int t = 0; t < 4; t++)
        af[t] = *(const short8*)&As[(wm + t * 16 + l16) * 64 + pc];
#pragma unroll
      for (int t = 0; t < 4; t++)
        bfr[t] = *(const short8*)&Bs[(wn + t * 16 + l16) * 64 + pc];
#pragma unroll
      for (int tm = 0; tm < 4; tm++)
#pragma unroll
        for (int tn = 0; tn < 4; tn++)
          acc[tm][tn] = __builtin_amdgcn_mfma_f32_16x16x32_bf16(af[tm], bfr[tn], acc[tm][tn], 0, 0, 0);
    }
  }

  // epilogue: C/D layout col = lane&15, row = quad*4 + reg  [m89-verified]
  const int row_base = bm * 128 + wm + quad * 4;
  const int col_base = bn * 128 + wn + l16;
  float dv[4];
  if (MODE == 1) {
#pragma unroll
    for (int tn = 0; tn < 4; tn++) dv[tn] = Dv[col_base + tn * 16];
  }
#pragma unroll
  for (int tm = 0; tm < 4; tm++) {
#pragma unroll
    for (int tn = 0; tn < 4; tn++) {
      int n = col_base + tn * 16;
#pragma unroll
      for (int r = 0; r < 4; r++) {
        int m = row_base + tm * 16 + r;
        float v = acc[tm][tn][r];
        if (MODE == 0) {
          outBf[(size_t)m * ND + n] = f2bf(v);
        } else {
          float uv = bf2f(ubf[(size_t)m * ND + n]);
          float ys = v + dv[tn] * uv;
          float y3 = ys * ys * ys;
          float t = tanhf(0.7978845608028654f * (ys + 0.044715f * y3));
          outF[(size_t)m * ND + n] = 0.5f * ys * (1.0f + t);
        }
      }
    }
  }
}

// ---------- scan pass 1: per-chunk carries (coalesced [m][n] reads) ----------
__global__ __launch_bounds__(256) void scan_carry(const u16* __restrict__ Bu,
                                                  const float2* __restrict__ lam,
                                                  float2* __restrict__ carry) {
  int p = threadIdx.x;
  int c = blockIdx.x;
  int b = blockIdx.y;
  float2 lm = lam[p];
  float xr = 0.f, xi = 0.f;
  const u16* base = Bu + ((size_t)b * SEQL + (size_t)c * CHUNK) * ND + 2 * p;
#pragma unroll
  for (int l = 0; l < CHUNK; l++) {
    unsigned w = *(const unsigned*)(base + (size_t)l * ND);
    float br = bf2f((u16)(w & 0xffffu));
    float bi = bf2f((u16)(w >> 16));
    float nr = lm.x * xr - lm.y * xi + br;
    float ni = lm.x * xi + lm.y * xr + bi;
    xr = nr; xi = ni;
  }
  carry[((size_t)b * NCH + c) * P + p] = make_float2(xr, xi);
}

// ---------- scan pass 2: sequential prefix over chunks ----------
__global__ __launch_bounds__(256) void scan_prefix(const float2* __restrict__ carry,
                                                   const float2* __restrict__ lam,
                                                   float2* __restrict__ prefix) {
  int p = threadIdx.x;
  int b = blockIdx.x;
  float2 lm = lam[p];
  float ar = lm.x, ai = lm.y;
  // lam^CHUNK, CHUNK = 32 = 2^5
#pragma unroll
  for (int i = 0; i < 5; i++) { float nr = ar * ar - ai * ai, ni = 2.f * ar * ai; ar = nr; ai = ni; }
  float pr = 0.f, pi = 0.f;
  for (int c = 0; c < NCH; c++) {
    prefix[((size_t)b * NCH + c) * P + p] = make_float2(pr, pi);
    float2 ca = carry[((size_t)b * NCH + c) * P + p];
    float nr = ar * pr - ai * pi + ca.x;
    float ni = ar * pi + ai * pr + ca.y;
    pr = nr; pi = ni;
  }
}

// ---------- scan pass 3: apply prefix, write xs in-place over Bu ----------
__global__ __launch_bounds__(256) void scan_apply(u16* __restrict__ Bu,
                                                  const float2* __restrict__ lam,
                                                  const float2* __restrict__ prefix) {
  int p = threadIdx.x;
  int c = blockIdx.x;
  int b = blockIdx.y;
  float2 lm = lam[p];
  float2 pf = prefix[((size_t)b * NCH + c) * P + p];
  float xr = pf.x, xi = pf.y;
  u16* base = Bu + ((size_t)b * SEQL + (size_t)c * CHUNK) * ND + 2 * p;
#pragma unroll
  for (int l = 0; l < CHUNK; l++) {
    unsigned* addr = (unsigned*)(base + (size_t)l * ND);
    unsigned w = *addr;
    float br = bf2f((u16)(w & 0xffffu));
    float bi = bf2f((u16)(w >> 16));
    float nr = lm.x * xr - lm.y * xi + br;
    float ni = lm.x * xi + lm.y * xr + bi;
    xr = nr; xi = ni;
    *addr = (unsigned)f2bf(nr) | ((unsigned)f2bf(ni) << 16);
  }
}

extern "C" void kernel_launch(void* const* d_in, const int* in_sizes, int n_in,
                              void* d_out, int out_size, void* d_ws, size_t ws_size,
                              hipStream_t stream) {
  const float* u      = (const float*)d_in[0];   // (8,4096,512)
  const float* Lre    = (const float*)d_in[1];   // (256,)
  const float* Lim    = (const float*)d_in[2];   // (256,)
  const float* Bin    = (const float*)d_in[3];   // (256,512,2)
  const float* Cin    = (const float*)d_in[4];   // (512,256,2)
  const float* Dv     = (const float*)d_in[5];   // (512,)
  const float* lstep  = (const float*)d_in[6];   // (256,1)
  float* out          = (float*)d_out;           // (8,4096,512) f32

  char* ws = (char*)d_ws;
  float2* lam    = (float2*)(ws + 0);                 //   2 KB
  float2* ffac   = (float2*)(ws + 2048);              //   2 KB
  u16*    bt1    = (u16*)   (ws + 4096);              // 512 KB
  u16*    bt2    = (u16*)   (ws + 528384);            // 512 KB
  u16*    ubf    = (u16*)   (ws + 1052672);           //  32 MB (u in bf16)
  u16*    Bu     = (u16*)   (ws + 34607104);          //  32 MB (becomes xs)
  float2* carry  = (float2*)(ws + 68161536);          //   2 MB
  float2* prefix = (float2*)(ws + 70258688);          //   2 MB

  setup_kernel<<<1, 256, 0, stream>>>(Lre, Lim, lstep, lam, ffac);
  bt1_kernel<<<(P * H) / 256, 256, 0, stream>>>((const float2*)Bin, ffac, bt1);
  bt2_kernel<<<(H * P * 2) / 256, 256, 0, stream>>>(Cin, bt2);
  ucvt_kernel<<<(M * H / 8) / 256, 256, 0, stream>>>((const float4*)u, (short8*)ubf);

  gemm_bt<0><<<dim3(M / 128, ND / 128), 256, 0, stream>>>(ubf, bt1, Bu, nullptr, nullptr, nullptr);

  scan_carry <<<dim3(NCH, BSZ), 256, 0, stream>>>(Bu, lam, carry);
  scan_prefix<<<BSZ, 256, 0, stream>>>(carry, lam, prefix);
  scan_apply <<<dim3(NCH, BSZ), 256, 0, stream>>>(Bu, lam, prefix);

  gemm_bt<1><<<dim3(M / 128, ND / 128), 256, 0, stream>>>(Bu, bt2, nullptr, out, Dv, ubf);
}